// Round 9
// baseline (349.161 us; speedup 1.0000x reference)
//
#include <hip/hip_runtime.h>
#include <hip/hip_bf16.h>

// MLA prefill: B=4 S=1024 H=32 NOPE=128 ROPE=64 VDIM=128 Q_LORA=1536 KV_LORA=512
// v9: GEMM redesigned from Little's-law analysis (r8: staging rate pinned at
// ~28 B/cyc/CU = in-flight/latency). Changes: 256x128 tile (85 FLOP/B), A+B
// triple-buffered (144 KiB, 512 thr, 1 blk/CU), stage FULL tile t+2 during t
// (48 KB in flight/CU), vmcnt(6) per K-tile. Fused grid 768+1024 = 7 exact
// rounds. Read path/swizzle/epilogue = verified v8. Prep/attn unchanged.

typedef __attribute__((ext_vector_type(8))) short s8v;
typedef __attribute__((ext_vector_type(4))) short s4v;
typedef __attribute__((ext_vector_type(4))) float f4v;

#define B_ 4
#define S_ 1024
#define H_ 32
#define SCALE_ 0.07216878364870322992f  // 1/sqrt(192)

__device__ __forceinline__ short f2bf(float f) {
  unsigned u = __builtin_bit_cast(unsigned, f);
  unsigned r = (u + 0x7FFFu + ((u >> 16) & 1u)) >> 16;
  return (short)(unsigned short)r;
}

// async global->LDS, 16B per lane; LDS dest = wave-uniform base + lane*16
__device__ __forceinline__ void gll16(const void* g, void* l) {
  __builtin_amdgcn_global_load_lds((const __attribute__((address_space(1))) void*)g,
                                   (__attribute__((address_space(3))) void*)l, 16, 0, 0);
}

// ---------------- prep: 4 converts + k_pe rope, one dispatch ----------------
__global__ __launch_bounds__(256) void prep_kernel(
    const float* __restrict__ Q, const float* __restrict__ WUQ,
    const float* __restrict__ KV, const float* __restrict__ WUKV,
    const float* __restrict__ PE, const float* __restrict__ cosb,
    const float* __restrict__ sinb,
    short* __restrict__ Qb, short* __restrict__ Wq,
    short* __restrict__ KVb, short* __restrict__ Wkv,
    short* __restrict__ kfull) {
  const int b = blockIdx.x;
  if (b < 21504) {
    int i = b * 256 + threadIdx.x;
    const float* src; short* dst;
    if (i < 1572864)      { src = Q;    dst = Qb; }
    else if (i < 3932160) { src = WUQ;  dst = Wq;  i -= 1572864; }
    else if (i < 4456448) { src = KV;   dst = KVb; i -= 3932160; }
    else                  { src = WUKV; dst = Wkv; i -= 4456448; }
    float4 v = reinterpret_cast<const float4*>(src)[i];
    s4v o;
    o[0] = f2bf(v.x); o[1] = f2bf(v.y); o[2] = f2bf(v.z); o[3] = f2bf(v.w);
    reinterpret_cast<s4v*>(dst)[i] = o;
  } else {
    const int pos = (b - 21504) * 4 + (threadIdx.x >> 6);  // 0..4095
    const int t = threadIdx.x & 63;
    const int p = t & 31;
    float x0 = PE[(size_t)pos * 64 + 2 * p];
    float x1 = PE[(size_t)pos * 64 + 2 * p + 1];
    float cv = cosb[(size_t)pos * 64 + p];
    float sv = sinb[(size_t)pos * 64 + p];
    float o = (t < 32) ? (x0 * cv - x1 * sv) : (x1 * cv + x0 * sv);
    short ob = f2bf(o);
    const int bb = pos >> 10, s = pos & 1023;
#pragma unroll
    for (int h = 0; h < H_; ++h)
      kfull[(((size_t)bb * H_ + h) * S_ + s) * 192 + 128 + t] = ob;
  }
}

// ---------------- 256x128 GEMM body, 3-buf, full-tile-ahead pipeline ----------------
// 512 threads = 8 waves (4M x 2N), per-wave 64x64, BK=64.
// MODE 0: q = A @ Bt^T, epilogue scale+rope -> out0=q_full [B][H][S][192]
// MODE 1: kv = A @ Bt^T, epilogue -> out0=k_full, out1=v^T [B][H][128][S]
template<int K, int MODE>
__device__ __forceinline__ void gemm_body(
    const int m0, const int n0, const short* __restrict__ A,
    const short* __restrict__ Bt, const float* __restrict__ cosb,
    const float* __restrict__ sinb, short* __restrict__ out0,
    short* __restrict__ out1, char* sAb, char* sBb) {
  constexpr int NT = K / 64;
  const int tid = threadIdx.x;
  const int w = tid >> 6, l = tid & 63;
  const int l15 = l & 15, lg = l >> 4;
  const int wr = (w >> 1) * 64;        // wm in [0,4): rows of 256
  const int wc = (w & 1) * 64;         // wn in [0,2): cols of 128
  const int rs7 = l15 & 7;
  f4v acc[4][4] = {};
  // staging: 512 threads cover 64 rows x 8 slots per gll16 (8 KB);
  // A tile = 4 calls (256 rows), B tile = 2 calls (128 rows).
  // LDS linear [rows][128B]; source pre-swizzled slot^(row&7) (64%8==0 ok).
  const int srow = tid >> 3;           // 0..63
  const int lslot = (tid & 7) ^ (srow & 7);
  const char* gA = (const char*)A + ((size_t)(m0 + srow) * K + lslot * 8) * 2;
  const char* gB = (const char*)Bt + ((size_t)(n0 + srow) * K + lslot * 8) * 2;
  const int ldst = tid * 16;

  auto stgA = [&](int buf, int kt) {
#pragma unroll
    for (int r4 = 0; r4 < 4; ++r4)
      gll16(gA + (size_t)r4 * (64 * K * 2) + kt * 128, sAb + buf * 32768 + r4 * 8192 + ldst);
  };
  auto stgB = [&](int buf, int kt) {
#pragma unroll
    for (int r4 = 0; r4 < 2; ++r4)
      gll16(gB + (size_t)r4 * (64 * K * 2) + kt * 128, sBb + buf * 16384 + r4 * 8192 + ldst);
  };

  // prologue: tiles 0,1 (12 loads); vmcnt(6): tile 0 landed, tile 1 in flight
  stgA(0, 0); stgB(0, 0);
  stgA(1, 1); stgB(1, 1);
  asm volatile("s_waitcnt vmcnt(6)" ::: "memory");
  __builtin_amdgcn_s_barrier();

  int bi = 0;                          // t % 3
  for (int t = 0; t < NT; ++t) {
    const char* bufA = sAb + bi * 32768;
    const char* bufB = sBb + bi * 16384;
    // stage tile t+2 into buffer (t+2)%3 == (t-1)%3: safe, all reads of t-1
    // completed before the t-1 -> t barrier.
    if (t + 2 < NT) {
      int b2 = bi + 2; if (b2 >= 3) b2 -= 3;
      stgA(b2, t + 2);
      stgB(b2, t + 2);
    }
    // B fragments to regs (8 reads), then MFMA with inline A reads
    s8v bf[2][4];
#pragma unroll
    for (int kc = 0; kc < 2; ++kc)
#pragma unroll
      for (int n = 0; n < 4; ++n)
        bf[kc][n] = *(const s8v*)(bufB + (wc + n * 16 + l15) * 128 + (((kc * 4 + lg) ^ rs7) << 4));
    __builtin_amdgcn_s_setprio(1);
#pragma unroll
    for (int kc = 0; kc < 2; ++kc)
#pragma unroll
      for (int i = 0; i < 4; ++i) {
        s8v af = *(const s8v*)(bufA + (wr + i * 16 + l15) * 128 + (((kc * 4 + lg) ^ rs7) << 4));
#pragma unroll
        for (int n = 0; n < 4; ++n)
          acc[i][n] = __builtin_amdgcn_mfma_f32_16x16x32_bf16(af, bf[kc][n], acc[i][n], 0, 0, 0);
      }
    __builtin_amdgcn_s_setprio(0);
    // boundary: tile t+1 must be landed; keep t+2's 6 loads in flight
    if (t + 2 < NT) asm volatile("s_waitcnt vmcnt(6)" ::: "memory");
    else            asm volatile("s_waitcnt vmcnt(0)" ::: "memory");
    __builtin_amdgcn_sched_barrier(0);
    __builtin_amdgcn_s_barrier();
    bi = (bi == 2) ? 0 : bi + 1;
  }

  // epilogue: C/D layout col=l15 (n), row=lg*4+r (m)
#pragma unroll
  for (int j = 0; j < 4; ++j) {
    const int colb = n0 + wc + j * 16;
    if (MODE == 0) {
      const int e0 = colb % 192;       // 192=12*16: frag never crosses a head
      const int h = colb / 192;
      const int e = e0 + l15;
      const bool is_pe = (e0 >= 128);
#pragma unroll
      for (int i = 0; i < 4; ++i) {
#pragma unroll
        for (int r = 0; r < 4; ++r) {
          const int row = m0 + wr + i * 16 + lg * 4 + r;  // b*1024+s
          const int b = row >> 10, s = row & 1023;
          const size_t base = ((size_t)(b * H_ + h) * S_ + s) * 192;
          float val = acc[i][j][r] * SCALE_;
          if (!is_pe) {
            out0[base + e] = f2bf(val);
          } else {
            float other = __shfl_xor(val, 1, 64);
            int p = (e - 128) >> 1;
            float cv = cosb[(size_t)row * 64 + p];
            float sv = sinb[(size_t)row * 64 + p];
            float o = ((l & 1) == 0) ? (val * cv - other * sv) : (val * cv + other * sv);
            int ep = ((l & 1) == 0) ? (128 + p) : (160 + p);
            out0[base + ep] = f2bf(o);
          }
        }
      }
    } else {
      const int e0 = colb % 256;       // 256=16*16: frag never crosses a head
      const int h = colb / 256;
      const int e = e0 + l15;
      const bool is_v = (e0 >= 128);
#pragma unroll
      for (int i = 0; i < 4; ++i) {
#pragma unroll
        for (int r = 0; r < 4; ++r) {
          const int row = m0 + wr + i * 16 + lg * 4 + r;
          const int b = row >> 10, s = row & 1023;
          float val = acc[i][j][r];
          if (!is_v) {
            out0[((size_t)(b * H_ + h) * S_ + s) * 192 + e] = f2bf(val);
          } else {
            out1[((size_t)(b * H_ + h) * 128 + (e - 128)) * S_ + s] = f2bf(val);
          }
        }
      }
    }
  }
}

// fused dispatch: [0,768) = gemm_q (16m x 48n), [768,1792) = gemm_kv (16m x 64n).
// 1792 = 7 exact rounds of 256 CUs at 1 block/CU. m-slab XCD map: xcd owns 2
// m-blocks (A-slab 1.6MB/0.5MB L2-resident); adjacent ids share n (B L2 reuse).
__global__ __launch_bounds__(512, 2) void gemm_fused(
    const short* __restrict__ Qb, const short* __restrict__ Wq,
    const short* __restrict__ KVb, const short* __restrict__ Wkv,
    const float* __restrict__ cosb, const float* __restrict__ sinb,
    short* __restrict__ qfull, short* __restrict__ kfull,
    short* __restrict__ vtb) {
  __shared__ char sAb[3 * 32768];      // 96 KiB
  __shared__ char sBb[3 * 16384];      // 48 KiB
  const int id = blockIdx.x;
  if (id < 768) {
    const int xcd = id & 7, j = id >> 3;           // j: 0..95
    const int m0 = (xcd * 2 + (j & 1)) * 256;
    const int n0 = (j >> 1) * 128;
    gemm_body<1536, 0>(m0, n0, Qb, Wq, cosb, sinb, qfull, nullptr, sAb, sBb);
  } else {
    const int idp = id - 768;
    const int xcd = idp & 7, j = idp >> 3;         // j: 0..127
    const int m0 = (xcd * 2 + (j & 1)) * 256;
    const int n0 = (j >> 1) * 128;
    gemm_body<512, 1>(m0, n0, KVb, Wkv, nullptr, nullptr, kfull, vtb, sAb, sBb);
  }
}

// ---------------- causal flash attention (v3, unchanged) ----------------
// q_full/k_full: [B*H][S][192] bf16 (q pre-scaled); vt: [B*H][128][S] bf16
// out: [B][S][H][128] f32. Block = 128 q rows (4 waves x 32), KV tile = 64.
// Swapped QK^T: S^T = mfma(K, Q): lane holds P[q=l&15][kv=k0+T*16+lg*4+r].
// Swapped PV:   O^T = mfma(V^T, P^T): acc D[col=l15=q][row=lg*4+r=d].
// V c2=0 half preloaded BEFORE K-prefetch issue; T13 defer-rescale (THR=8).
__global__ __launch_bounds__(256, 2) void attn_kernel(
    const short* __restrict__ qfull, const short* __restrict__ kfull,
    const short* __restrict__ vt, float* __restrict__ out) {
  __shared__ short sK[2][64 * 192];     // double-buffered K tile, 48 KiB
  const int bid = blockIdx.x;
  const int qb = 7 - (bid >> 7);        // longest blocks first
  const int bh = bid & 127;
  const int b = bh >> 5, h = bh & 31;
  const int tid = threadIdx.x;
  const int w = tid >> 6, l = tid & 63;
  const int l15 = l & 15, lg = l >> 4;
  const short* Qh = qfull + (size_t)bh * (S_ * 192);
  const char*  KhB = (const char*)(kfull + (size_t)bh * (S_ * 192));
  const short* Vh = vt + (size_t)bh * (128 * S_);
  const int qw = qb * 128 + w * 32;     // this wave's q base (32 rows)

  // Q fragments (B-operand: lane l15 = q col, k = kc*32+lg*8..+7)
  s8v qfr[2][6];
#pragma unroll
  for (int mq = 0; mq < 2; ++mq)
#pragma unroll
    for (int kc = 0; kc < 6; ++kc)
      qfr[mq][kc] = *reinterpret_cast<const s8v*>(
          &Qh[(size_t)(qw + mq * 16 + l15) * 192 + kc * 32 + lg * 8]);

  // K staging offsets: LDS linear; source pre-swizzled (c ^ ((row&7)<<4)) so
  // readers at row*384 + (cw ^ swz) get K[row][cw] conflict-free.
  unsigned kOff[6];
#pragma unroll
  for (int c = 0; c < 6; ++c) {
    unsigned o = (unsigned)(w * 6 + c) * 1024u + (unsigned)l * 16u;
    unsigned row = o / 384u;
    unsigned cb = o - row * 384u;
    kOff[c] = row * 384u + (cb ^ ((row & 7u) << 4));
  }

  // prologue: stage tile 0 into buf 0
#pragma unroll
  for (int c = 0; c < 6; ++c)
    gll16(KhB + kOff[c], (char*)(&sK[0][0]) + (w * 6 + c) * 1024);
  __syncthreads();

  f4v acc[8][2] = {};
  float mrun[2] = {-3.0e38f, -3.0e38f};
  float lsum[2] = {0.f, 0.f};
  const int nt = 2 * (qb + 1);
  int cur = 0;
  for (int t = 0; t < nt; ++t) {
    const int k0 = t * 64;
    const bool compute = (k0 <= qw + 31);   // wave-uniform causal skip
    s8v vf0[8];
    if (compute) {                      // V c2=0 preload (oldest VMEM this tile)
#pragma unroll
      for (int dt = 0; dt < 8; ++dt)
        vf0[dt] = *reinterpret_cast<const s8v*>(
            &Vh[(size_t)(dt * 16 + l15) * S_ + k0 + lg * 8]);
    }
    if (t + 1 < nt) {                   // prefetch next K tile (newest VMEM)
      const char* gb = KhB + (size_t)(t + 1) * (64 * 384);
      char* lb = (char*)(&sK[cur ^ 1][0]);
#pragma unroll
      for (int c = 0; c < 6; ++c)
        gll16(gb + kOff[c], lb + (w * 6 + c) * 1024);
    }
    if (compute) {
      const char* sKc = (const char*)(&sK[cur][0]);
      f4v s[4][2] = {};
#pragma unroll
      for (int T = 0; T < 4; ++T) {
        const int row = T * 16 + l15;
        const unsigned swz = (unsigned)((row & 7) << 4);
#pragma unroll
        for (int kc = 0; kc < 6; ++kc) {
          s8v kf = *reinterpret_cast<const s8v*>(
              sKc + row * 384 + (unsigned)((kc * 64 + lg * 16) ^ swz));
          s[T][0] = __builtin_amdgcn_mfma_f32_16x16x32_bf16(kf, qfr[0][kc], s[T][0], 0, 0, 0);
          s[T][1] = __builtin_amdgcn_mfma_f32_16x16x32_bf16(kf, qfr[1][kc], s[T][1], 0, 0, 0);
        }
      }
      const bool diag = (t >= 2 * qb);
      unsigned pk[4][2][2];
#pragma unroll
      for (int mq = 0; mq < 2; ++mq) {
        const int qlane = qw + mq * 16 + l15;
        if (diag) {
#pragma unroll
          for (int T = 0; T < 4; ++T)
#pragma unroll
            for (int r = 0; r < 4; ++r)
              if (k0 + T * 16 + lg * 4 + r > qlane) s[T][mq][r] = -1.0e30f;
        }
        float tmax = s[0][mq][0];
#pragma unroll
        for (int T = 0; T < 4; ++T)
#pragma unroll
          for (int r = 0; r < 4; ++r) tmax = fmaxf(tmax, s[T][mq][r]);
        tmax = fmaxf(tmax, __shfl_xor(tmax, 16, 64));
        tmax = fmaxf(tmax, __shfl_xor(tmax, 32, 64));
        // T13 defer-rescale: skip O/l rescale while max growth <= 8
        if (!__all(tmax <= mrun[mq] + 8.0f)) {
          const float mnew = fmaxf(mrun[mq], tmax);
          const float cf = __expf(mrun[mq] - mnew);
          mrun[mq] = mnew;
          lsum[mq] *= cf;
#pragma unroll
          for (int dt = 0; dt < 8; ++dt)
#pragma unroll
            for (int r = 0; r < 4; ++r) acc[dt][mq][r] *= cf;
        }
        float rs = 0.f;
#pragma unroll
        for (int T = 0; T < 4; ++T)
#pragma unroll
          for (int r = 0; r < 4; ++r) {
            float e = __expf(s[T][mq][r] - mrun[mq]);   // bounded by e^8
            s[T][mq][r] = e;
            rs += e;
          }
        rs += __shfl_xor(rs, 16, 64);
        rs += __shfl_xor(rs, 32, 64);
        lsum[mq] += rs;
#pragma unroll
        for (int T = 0; T < 4; ++T) {
          pk[T][mq][0] = (unsigned)(unsigned short)f2bf(s[T][mq][0]) |
                         ((unsigned)(unsigned short)f2bf(s[T][mq][1]) << 16);
          pk[T][mq][1] = (unsigned)(unsigned short)f2bf(s[T][mq][2]) |
                         ((unsigned)(unsigned short)f2bf(s[T][mq][3]) << 16);
        }
      }
      // PV: B-frag word j2 of chunk c2 = pk[2c2+(lg>>1)][j2&1] from lane
      // l15 + 16*((lg&1)*2 + (j2>>1))  (derived + verified lane mapping)
#pragma unroll
      for (int c2 = 0; c2 < 2; ++c2) {
        union { unsigned u[4]; s8v v; } bb[2];
#pragma unroll
        for (int mq = 0; mq < 2; ++mq)
#pragma unroll
          for (int j2 = 0; j2 < 4; ++j2) {
            int src = l15 + ((l & 16) << 1) + ((j2 & 2) << 3);
            unsigned va = (unsigned)__shfl((int)pk[2 * c2][mq][j2 & 1], src, 64);
            unsigned vb = (unsigned)__shfl((int)pk[2 * c2 + 1][mq][j2 & 1], src, 64);
            bb[mq].u[j2] = (l & 32) ? vb : va;
          }
#pragma unroll
        for (int dt = 0; dt < 8; ++dt) {
          s8v vfx = (c2 == 0) ? vf0[dt]
                              : *reinterpret_cast<const s8v*>(
                                    &Vh[(size_t)(dt * 16 + l15) * S_ + k0 + 32 + lg * 8]);
          acc[dt][0] = __builtin_amdgcn_mfma_f32_16x16x32_bf16(vfx, bb[0].v, acc[dt][0], 0, 0, 0);
          acc[dt][1] = __builtin_amdgcn_mfma_f32_16x16x32_bf16(vfx, bb[1].v, acc[dt][1], 0, 0, 0);
        }
      }
    }
    __syncthreads();                    // tile boundary (drains prefetch)
    cur ^= 1;
  }
  // epilogue: O[q][d], 64B-coalesced float4 stores
#pragma unroll
  for (int mq = 0; mq < 2; ++mq) {
    const float inv = 1.0f / lsum[mq];
    const int q = qw + mq * 16 + l15;
    float* ob = out + (((size_t)b * S_ + q) * H_ + h) * 128 + lg * 4;
#pragma unroll
    for (int dt = 0; dt < 8; ++dt) {
      float4 o4 = { acc[dt][mq][0] * inv, acc[dt][mq][1] * inv,
                    acc[dt][mq][2] * inv, acc[dt][mq][3] * inv };
      *reinterpret_cast<float4*>(ob + dt * 16) = o4;
    }
  }
}

// ---------------- launch ----------------
extern "C" void kernel_launch(void* const* d_in, const int* in_sizes, int n_in,
                              void* d_out, int out_size, void* d_ws, size_t ws_size,
                              hipStream_t stream) {
  const float* Q    = (const float*)d_in[0];
  const float* KV   = (const float*)d_in[1];
  const float* PE   = (const float*)d_in[2];
  const float* WUQ  = (const float*)d_in[3];
  const float* WUKV = (const float*)d_in[4];
  const float* cosb = (const float*)d_in[5];
  const float* sinb = (const float*)d_in[6];
  float* out = (float*)d_out;
  char* ws = (char*)d_ws;

  short* Qb    = (short*)(ws);                   // 4096*1536*2  = 12,582,912
  short* Wq    = (short*)(ws + 12582912);        // 6144*1536*2  = 18,874,368
  short* KVb   = (short*)(ws + 31457280);        // 4096*512*2   =  4,194,304
  short* Wkv   = (short*)(ws + 35651584);        // 8192*512*2   =  8,388,608
  short* qfull = (short*)(ws + 44040192);        // 4*32*1024*192*2 = 50,331,648
  short* kfull = (short*)(ws + 94371840);        // 50,331,648
  short* vtb   = (short*)(ws + 144703488);       // 4*32*128*1024*2 = 33,554,432

  prep_kernel<<<22528, 256, 0, stream>>>(Q, WUQ, KV, WUKV, PE, cosb, sinb,
                                         Qb, Wq, KVb, Wkv, kfull);
  gemm_fused<<<1792, 512, 0, stream>>>(Qb, Wq, KVb, Wkv, cosb, sinb,
                                       qfull, kfull, vtb);
  attn_kernel<<<1024, 256, 0, stream>>>(qfull, kfull, vtb, out);
}

// Round 11
// 284.273 us; speedup vs baseline: 1.2283x; 1.2283x over previous
//
#include <hip/hip_runtime.h>
#include <hip/hip_bf16.h>

// MLA prefill: B=4 S=1024 H=32 NOPE=128 ROPE=64 VDIM=128 Q_LORA=1536 KV_LORA=512
// v11: v10 with the staging-offset bug fixed (kk*2 bytes, NOT kk*128 — kk is
// an ELEMENT offset; v10 staged garbage). gemm single-buffered (32 KiB LDS ->
// ~4-5 blocks/CU): hypothesis = cross-block TLP hides the per-step vmcnt(0)
// drain (m97 ran this exact 2-barrier structure at ~3 blocks/CU, 874 TF).
// Prep/attn unchanged from v8 (verified).

typedef __attribute__((ext_vector_type(8))) short s8v;
typedef __attribute__((ext_vector_type(4))) short s4v;
typedef __attribute__((ext_vector_type(4))) float f4v;

#define B_ 4
#define S_ 1024
#define H_ 32
#define SCALE_ 0.07216878364870322992f  // 1/sqrt(192)

__device__ __forceinline__ short f2bf(float f) {
  unsigned u = __builtin_bit_cast(unsigned, f);
  unsigned r = (u + 0x7FFFu + ((u >> 16) & 1u)) >> 16;
  return (short)(unsigned short)r;
}

// async global->LDS, 16B per lane; LDS dest = wave-uniform base + lane*16
__device__ __forceinline__ void gll16(const void* g, void* l) {
  __builtin_amdgcn_global_load_lds((const __attribute__((address_space(1))) void*)g,
                                   (__attribute__((address_space(3))) void*)l, 16, 0, 0);
}

// ---------------- prep: 4 converts + k_pe rope, one dispatch ----------------
__global__ __launch_bounds__(256) void prep_kernel(
    const float* __restrict__ Q, const float* __restrict__ WUQ,
    const float* __restrict__ KV, const float* __restrict__ WUKV,
    const float* __restrict__ PE, const float* __restrict__ cosb,
    const float* __restrict__ sinb,
    short* __restrict__ Qb, short* __restrict__ Wq,
    short* __restrict__ KVb, short* __restrict__ Wkv,
    short* __restrict__ kfull) {
  const int b = blockIdx.x;
  if (b < 21504) {
    int i = b * 256 + threadIdx.x;
    const float* src; short* dst;
    if (i < 1572864)      { src = Q;    dst = Qb; }
    else if (i < 3932160) { src = WUQ;  dst = Wq;  i -= 1572864; }
    else if (i < 4456448) { src = KV;   dst = KVb; i -= 3932160; }
    else                  { src = WUKV; dst = Wkv; i -= 4456448; }
    float4 v = reinterpret_cast<const float4*>(src)[i];
    s4v o;
    o[0] = f2bf(v.x); o[1] = f2bf(v.y); o[2] = f2bf(v.z); o[3] = f2bf(v.w);
    reinterpret_cast<s4v*>(dst)[i] = o;
  } else {
    const int pos = (b - 21504) * 4 + (threadIdx.x >> 6);  // 0..4095
    const int t = threadIdx.x & 63;
    const int p = t & 31;
    float x0 = PE[(size_t)pos * 64 + 2 * p];
    float x1 = PE[(size_t)pos * 64 + 2 * p + 1];
    float cv = cosb[(size_t)pos * 64 + p];
    float sv = sinb[(size_t)pos * 64 + p];
    float o = (t < 32) ? (x0 * cv - x1 * sv) : (x1 * cv + x0 * sv);
    short ob = f2bf(o);
    const int bb = pos >> 10, s = pos & 1023;
#pragma unroll
    for (int h = 0; h < H_; ++h)
      kfull[(((size_t)bb * H_ + h) * S_ + s) * 192 + 128 + t] = ob;
  }
}

// ---------------- 128x128 GEMM body, single-buffered, BK=64 ----------------
// MODE 0: q = A @ Bt^T, epilogue scale+rope -> out0=q_full [B][H][S][192]
// MODE 1: kv = A @ Bt^T, epilogue -> out0=k_full, out1=v^T [B][H][128][S]
template<int K, int MODE>
__device__ __forceinline__ void gemm_body(
    const int m0, const int n0, const short* __restrict__ A,
    const short* __restrict__ Bt, const float* __restrict__ cosb,
    const float* __restrict__ sinb, short* __restrict__ out0,
    short* __restrict__ out1, char* sAb, char* sBb) {
  const int tid = threadIdx.x;
  const int w = tid >> 6, l = tid & 63;
  const int l15 = l & 15, lg = l >> 4;
  const int wr = (w >> 1) * 64, wc = (w & 1) * 64;
  const int rs7 = l15 & 7;
  f4v acc[4][4] = {};
  // staging: thread covers row (tid>>3)+32*r4, phys slot tid&7; LDS linear,
  // source pre-swizzled (logical slot = phys ^ (row&7)).
  const int srow = tid >> 3;
  const int swsl = (tid & 7) ^ (srow & 7);
  const char* gA = (const char*)A + ((size_t)(m0 + srow) * K + swsl * 8) * 2;
  const char* gB = (const char*)Bt + ((size_t)(n0 + srow) * K + swsl * 8) * 2;
  const int ldst = tid * 16;

  for (int kk = 0; kk < K; kk += 64) {
    // stage tile kk (8 x gll16); kk is an ELEMENT offset -> byte offset kk*2
#pragma unroll
    for (int r4 = 0; r4 < 4; ++r4) {
      gll16(gA + (size_t)r4 * (32 * K * 2) + (size_t)kk * 2, sAb + r4 * 4096 + ldst);
      gll16(gB + (size_t)r4 * (32 * K * 2) + (size_t)kk * 2, sBb + r4 * 4096 + ldst);
    }
    __syncthreads();                   // vmcnt(0) drain -> tile visible
#pragma unroll
    for (int kc = 0; kc < 2; ++kc) {
      s8v af[4], bfv[4];
#pragma unroll
      for (int x = 0; x < 4; ++x) {
        af[x]  = *(const s8v*)(sAb + (wr + x * 16 + l15) * 128 + (((kc * 4 + lg) ^ rs7) << 4));
        bfv[x] = *(const s8v*)(sBb + (wc + x * 16 + l15) * 128 + (((kc * 4 + lg) ^ rs7) << 4));
      }
#pragma unroll
      for (int i = 0; i < 4; ++i)
#pragma unroll
        for (int j = 0; j < 4; ++j)
          acc[i][j] = __builtin_amdgcn_mfma_f32_16x16x32_bf16(af[i], bfv[j], acc[i][j], 0, 0, 0);
    }
    __syncthreads();                   // all reads done before next overwrite
  }

  // epilogue: C/D layout col=l15 (n), row=lg*4+r (m)
#pragma unroll
  for (int j = 0; j < 4; ++j) {
    const int colb = n0 + wc + j * 16;
    if (MODE == 0) {
      const int e0 = colb % 192;       // 192=12*16: frag never crosses a head
      const int h = colb / 192;
      const int e = e0 + l15;
      const bool is_pe = (e0 >= 128);
#pragma unroll
      for (int i = 0; i < 4; ++i) {
#pragma unroll
        for (int r = 0; r < 4; ++r) {
          const int row = m0 + wr + i * 16 + lg * 4 + r;  // b*1024+s
          const int b = row >> 10, s = row & 1023;
          const size_t base = ((size_t)(b * H_ + h) * S_ + s) * 192;
          float val = acc[i][j][r] * SCALE_;
          if (!is_pe) {
            out0[base + e] = f2bf(val);
          } else {
            float other = __shfl_xor(val, 1, 64);
            int p = (e - 128) >> 1;
            float cv = cosb[(size_t)row * 64 + p];
            float sv = sinb[(size_t)row * 64 + p];
            float o = ((l & 1) == 0) ? (val * cv - other * sv) : (val * cv + other * sv);
            int ep = ((l & 1) == 0) ? (128 + p) : (160 + p);
            out0[base + ep] = f2bf(o);
          }
        }
      }
    } else {
      const int e0 = colb % 256;       // 256=16*16: frag never crosses a head
      const int h = colb / 256;
      const int e = e0 + l15;
      const bool is_v = (e0 >= 128);
#pragma unroll
      for (int i = 0; i < 4; ++i) {
#pragma unroll
        for (int r = 0; r < 4; ++r) {
          const int row = m0 + wr + i * 16 + lg * 4 + r;
          const int b = row >> 10, s = row & 1023;
          float val = acc[i][j][r];
          if (!is_v) {
            out0[((size_t)(b * H_ + h) * S_ + s) * 192 + e] = f2bf(val);
          } else {
            out1[((size_t)(b * H_ + h) * 128 + (e - 128)) * S_ + s] = f2bf(val);
          }
        }
      }
    }
  }
}

// fused dispatch: blocks [0,1536) = gemm_q, [1536,3584) = gemm_kv.
// m-slab XCD map: xcd = id%8 owns m-blocks [4*xcd, 4*xcd+4) (A-slab
// 1.6MB / 0.5MB -> L2-resident), n advances every 4 ids.
__global__ __launch_bounds__(256, 4) void gemm_fused(
    const short* __restrict__ Qb, const short* __restrict__ Wq,
    const short* __restrict__ KVb, const short* __restrict__ Wkv,
    const float* __restrict__ cosb, const float* __restrict__ sinb,
    short* __restrict__ qfull, short* __restrict__ kfull,
    short* __restrict__ vtb) {
  __shared__ char sAb[16384];          // single-buffered: 32 KiB total
  __shared__ char sBb[16384];
  const int id = blockIdx.x;
  if (id < 1536) {
    const int xcd = id & 7, j = id >> 3;           // j: 0..191 = 4m x 48n
    const int m0 = (xcd * 4 + (j & 3)) * 128;
    const int n0 = (j >> 2) * 128;
    gemm_body<1536, 0>(m0, n0, Qb, Wq, cosb, sinb, qfull, nullptr, sAb, sBb);
  } else {
    const int idp = id - 1536;                     // 1536%8==0: xcd = idp%8
    const int xcd = idp & 7, j = idp >> 3;         // j: 0..255 = 4m x 64n
    const int m0 = (xcd * 4 + (j & 3)) * 128;
    const int n0 = (j >> 2) * 128;
    gemm_body<512, 1>(m0, n0, KVb, Wkv, nullptr, nullptr, kfull, vtb, sAb, sBb);
  }
}

// ---------------- causal flash attention (v3, unchanged) ----------------
// q_full/k_full: [B*H][S][192] bf16 (q pre-scaled); vt: [B*H][128][S] bf16
// out: [B][S][H][128] f32. Block = 128 q rows (4 waves x 32), KV tile = 64.
// Swapped QK^T: S^T = mfma(K, Q): lane holds P[q=l&15][kv=k0+T*16+lg*4+r].
// Swapped PV:   O^T = mfma(V^T, P^T): acc D[col=l15=q][row=lg*4+r=d].
// V c2=0 half preloaded BEFORE K-prefetch issue; T13 defer-rescale (THR=8).
__global__ __launch_bounds__(256, 2) void attn_kernel(
    const short* __restrict__ qfull, const short* __restrict__ kfull,
    const short* __restrict__ vt, float* __restrict__ out) {
  __shared__ short sK[2][64 * 192];     // double-buffered K tile, 48 KiB
  const int bid = blockIdx.x;
  const int qb = 7 - (bid >> 7);        // longest blocks first
  const int bh = bid & 127;
  const int b = bh >> 5, h = bh & 31;
  const int tid = threadIdx.x;
  const int w = tid >> 6, l = tid & 63;
  const int l15 = l & 15, lg = l >> 4;
  const short* Qh = qfull + (size_t)bh * (S_ * 192);
  const char*  KhB = (const char*)(kfull + (size_t)bh * (S_ * 192));
  const short* Vh = vt + (size_t)bh * (128 * S_);
  const int qw = qb * 128 + w * 32;     // this wave's q base (32 rows)

  // Q fragments (B-operand: lane l15 = q col, k = kc*32+lg*8..+7)
  s8v qfr[2][6];
#pragma unroll
  for (int mq = 0; mq < 2; ++mq)
#pragma unroll
    for (int kc = 0; kc < 6; ++kc)
      qfr[mq][kc] = *reinterpret_cast<const s8v*>(
          &Qh[(size_t)(qw + mq * 16 + l15) * 192 + kc * 32 + lg * 8]);

  // K staging offsets: LDS linear; source pre-swizzled (c ^ ((row&7)<<4)) so
  // readers at row*384 + (cw ^ swz) get K[row][cw] conflict-free.
  unsigned kOff[6];
#pragma unroll
  for (int c = 0; c < 6; ++c) {
    unsigned o = (unsigned)(w * 6 + c) * 1024u + (unsigned)l * 16u;
    unsigned row = o / 384u;
    unsigned cb = o - row * 384u;
    kOff[c] = row * 384u + (cb ^ ((row & 7u) << 4));
  }

  // prologue: stage tile 0 into buf 0
#pragma unroll
  for (int c = 0; c < 6; ++c)
    gll16(KhB + kOff[c], (char*)(&sK[0][0]) + (w * 6 + c) * 1024);
  __syncthreads();

  f4v acc[8][2] = {};
  float mrun[2] = {-3.0e38f, -3.0e38f};
  float lsum[2] = {0.f, 0.f};
  const int nt = 2 * (qb + 1);
  int cur = 0;
  for (int t = 0; t < nt; ++t) {
    const int k0 = t * 64;
    const bool compute = (k0 <= qw + 31);   // wave-uniform causal skip
    s8v vf0[8];
    if (compute) {                      // V c2=0 preload (oldest VMEM this tile)
#pragma unroll
      for (int dt = 0; dt < 8; ++dt)
        vf0[dt] = *reinterpret_cast<const s8v*>(
            &Vh[(size_t)(dt * 16 + l15) * S_ + k0 + lg * 8]);
    }
    if (t + 1 < nt) {                   // prefetch next K tile (newest VMEM)
      const char* gb = KhB + (size_t)(t + 1) * (64 * 384);
      char* lb = (char*)(&sK[cur ^ 1][0]);
#pragma unroll
      for (int c = 0; c < 6; ++c)
        gll16(gb + kOff[c], lb + (w * 6 + c) * 1024);
    }
    if (compute) {
      const char* sKc = (const char*)(&sK[cur][0]);
      f4v s[4][2] = {};
#pragma unroll
      for (int T = 0; T < 4; ++T) {
        const int row = T * 16 + l15;
        const unsigned swz = (unsigned)((row & 7) << 4);
#pragma unroll
        for (int kc = 0; kc < 6; ++kc) {
          s8v kf = *reinterpret_cast<const s8v*>(
              sKc + row * 384 + (unsigned)((kc * 64 + lg * 16) ^ swz));
          s[T][0] = __builtin_amdgcn_mfma_f32_16x16x32_bf16(kf, qfr[0][kc], s[T][0], 0, 0, 0);
          s[T][1] = __builtin_amdgcn_mfma_f32_16x16x32_bf16(kf, qfr[1][kc], s[T][1], 0, 0, 0);
        }
      }
      const bool diag = (t >= 2 * qb);
      unsigned pk[4][2][2];
#pragma unroll
      for (int mq = 0; mq < 2; ++mq) {
        const int qlane = qw + mq * 16 + l15;
        if (diag) {
#pragma unroll
          for (int T = 0; T < 4; ++T)
#pragma unroll
            for (int r = 0; r < 4; ++r)
              if (k0 + T * 16 + lg * 4 + r > qlane) s[T][mq][r] = -1.0e30f;
        }
        float tmax = s[0][mq][0];
#pragma unroll
        for (int T = 0; T < 4; ++T)
#pragma unroll
          for (int r = 0; r < 4; ++r) tmax = fmaxf(tmax, s[T][mq][r]);
        tmax = fmaxf(tmax, __shfl_xor(tmax, 16, 64));
        tmax = fmaxf(tmax, __shfl_xor(tmax, 32, 64));
        // T13 defer-rescale: skip O/l rescale while max growth <= 8
        if (!__all(tmax <= mrun[mq] + 8.0f)) {
          const float mnew = fmaxf(mrun[mq], tmax);
          const float cf = __expf(mrun[mq] - mnew);
          mrun[mq] = mnew;
          lsum[mq] *= cf;
#pragma unroll
          for (int dt = 0; dt < 8; ++dt)
#pragma unroll
            for (int r = 0; r < 4; ++r) acc[dt][mq][r] *= cf;
        }
        float rs = 0.f;
#pragma unroll
        for (int T = 0; T < 4; ++T)
#pragma unroll
          for (int r = 0; r < 4; ++r) {
            float e = __expf(s[T][mq][r] - mrun[mq]);   // bounded by e^8
            s[T][mq][r] = e;
            rs += e;
          }
        rs += __shfl_xor(rs, 16, 64);
        rs += __shfl_xor(rs, 32, 64);
        lsum[mq] += rs;
#pragma unroll
        for (int T = 0; T < 4; ++T) {
          pk[T][mq][0] = (unsigned)(unsigned short)f2bf(s[T][mq][0]) |
                         ((unsigned)(unsigned short)f2bf(s[T][mq][1]) << 16);
          pk[T][mq][1] = (unsigned)(unsigned short)f2bf(s[T][mq][2]) |
                         ((unsigned)(unsigned short)f2bf(s[T][mq][3]) << 16);
        }
      }
      // PV: B-frag word j2 of chunk c2 = pk[2c2+(lg>>1)][j2&1] from lane
      // l15 + 16*((lg&1)*2 + (j2>>1))  (derived + verified lane mapping)
#pragma unroll
      for (int c2 = 0; c2 < 2; ++c2) {
        union { unsigned u[4]; s8v v; } bb[2];
#pragma unroll
        for (int mq = 0; mq < 2; ++mq)
#pragma unroll
          for (int j2 = 0; j2 < 4; ++j2) {
            int src = l15 + ((l & 16) << 1) + ((j2 & 2) << 3);
            unsigned va = (unsigned)__shfl((int)pk[2 * c2][mq][j2 & 1], src, 64);
            unsigned vb = (unsigned)__shfl((int)pk[2 * c2 + 1][mq][j2 & 1], src, 64);
            bb[mq].u[j2] = (l & 32) ? vb : va;
          }
#pragma unroll
        for (int dt = 0; dt < 8; ++dt) {
          s8v vfx = (c2 == 0) ? vf0[dt]
                              : *reinterpret_cast<const s8v*>(
                                    &Vh[(size_t)(dt * 16 + l15) * S_ + k0 + 32 + lg * 8]);
          acc[dt][0] = __builtin_amdgcn_mfma_f32_16x16x32_bf16(vfx, bb[0].v, acc[dt][0], 0, 0, 0);
          acc[dt][1] = __builtin_amdgcn_mfma_f32_16x16x32_bf16(vfx, bb[1].v, acc[dt][1], 0, 0, 0);
        }
      }
    }
    __syncthreads();                    // tile boundary (drains prefetch)
    cur ^= 1;
  }
  // epilogue: O[q][d], 64B-coalesced float4 stores
#pragma unroll
  for (int mq = 0; mq < 2; ++mq) {
    const float inv = 1.0f / lsum[mq];
    const int q = qw + mq * 16 + l15;
    float* ob = out + (((size_t)b * S_ + q) * H_ + h) * 128 + lg * 4;
#pragma unroll
    for (int dt = 0; dt < 8; ++dt) {
      float4 o4 = { acc[dt][mq][0] * inv, acc[dt][mq][1] * inv,
                    acc[dt][mq][2] * inv, acc[dt][mq][3] * inv };
      *reinterpret_cast<float4*>(ob + dt * 16) = o4;
    }
  }
}

// ---------------- launch ----------------
extern "C" void kernel_launch(void* const* d_in, const int* in_sizes, int n_in,
                              void* d_out, int out_size, void* d_ws, size_t ws_size,
                              hipStream_t stream) {
  const float* Q    = (const float*)d_in[0];
  const float* KV   = (const float*)d_in[1];
  const float* PE   = (const float*)d_in[2];
  const float* WUQ  = (const float*)d_in[3];
  const float* WUKV = (const float*)d_in[4];
  const float* cosb = (const float*)d_in[5];
  const float* sinb = (const float*)d_in[6];
  float* out = (float*)d_out;
  char* ws = (char*)d_ws;

  short* Qb    = (short*)(ws);                   // 4096*1536*2  = 12,582,912
  short* Wq    = (short*)(ws + 12582912);        // 6144*1536*2  = 18,874,368
  short* KVb   = (short*)(ws + 31457280);        // 4096*512*2   =  4,194,304
  short* Wkv   = (short*)(ws + 35651584);        // 8192*512*2   =  8,388,608
  short* qfull = (short*)(ws + 44040192);        // 4*32*1024*192*2 = 50,331,648
  short* kfull = (short*)(ws + 94371840);        // 50,331,648
  short* vtb   = (short*)(ws + 144703488);       // 4*32*128*1024*2 = 33,554,432

  prep_kernel<<<22528, 256, 0, stream>>>(Q, WUQ, KV, WUKV, PE, cosb, sinb,
                                         Qb, Wq, KVb, Wkv, kfull);
  gemm_fused<<<3584, 256, 0, stream>>>(Qb, Wq, KVb, Wkv, cosb, sinb,
                                       qfull, kfull, vtb);
  attn_kernel<<<1024, 256, 0, stream>>>(qfull, kfull, vtb, out);
}